// Round 1
// baseline (940.470 us; speedup 1.0000x reference)
//
#include <hip/hip_runtime.h>
#include <cstddef>

// Problem constants (B,T,D,H) = (64,512,2048,128)
#define BB 64
#define TT 512
#define DD 2048
#define HH 128
#define M1 (BB*TT)   // 32768 rows for both GEMMs

__device__ __forceinline__ float tanh_fast(float x) {
    // tanh(x) = 1 - 2/(e^{2x}+1); e^{2x} = exp2(x * 2*log2(e))
    float e2x = __builtin_amdgcn_exp2f(x * 2.885390081777927f);
    return 1.0f - 2.0f * __builtin_amdgcn_rcpf(e2x + 1.0f);
}

// ---------------------------------------------------------------------------
// GEMM: out[m][n] = sum_k A[m][k]*W[n][k] + bia[n] + bib[n]
// A: [M1][K] row-major, W: [128][K] row-major, out: [M1][128]
// BM=64, BN=128, BK=16, 256 threads, thread tile 4x8.
// ---------------------------------------------------------------------------
template<int K>
__global__ __launch_bounds__(256) void gemm_bias_kernel(
    const float* __restrict__ A, const float* __restrict__ W,
    const float* __restrict__ bia, const float* __restrict__ bib,
    float* __restrict__ out)
{
    constexpr int BM = 64, BK = 16;
    constexpr int NK = K / BK;
    __shared__ float As[BK][68];    // [k][m], pad 68 -> staging writes 2-way max
    __shared__ float Bs[BK][132];   // [k][n], pad 132

    const int tid = threadIdx.x;
    const int tc = tid & 15;        // col group: cols {4tc..4tc+3, 64+4tc..+3}
    const int tr = tid >> 4;        // row group: rows tr*4..tr*4+3
    const size_t m0 = (size_t)blockIdx.x * BM;

    // global->reg staging indices
    const int arow = tid >> 2;            // 0..63
    const int ak4  = (tid & 3) * 4;       // 0,4,8,12
    const int bn0  = tid >> 1;            // 0..127
    const int bk   = (tid & 1) * 8;       // 0 or 8

    const float* Aptr = A + (m0 + arow) * (size_t)K + ak4;
    const float* Wptr = W + (size_t)bn0 * K + bk;

    float4 ra  = *(const float4*)Aptr;
    float4 rb0 = *(const float4*)(Wptr);
    float4 rb1 = *(const float4*)(Wptr + 4);

    float acc[4][8];
#pragma unroll
    for (int i = 0; i < 4; i++)
#pragma unroll
        for (int j = 0; j < 8; j++) acc[i][j] = 0.0f;

    for (int kt = 0; kt < NK; ++kt) {
        __syncthreads();
        As[ak4 + 0][arow] = ra.x;
        As[ak4 + 1][arow] = ra.y;
        As[ak4 + 2][arow] = ra.z;
        As[ak4 + 3][arow] = ra.w;
        Bs[bk + 0][bn0] = rb0.x;
        Bs[bk + 1][bn0] = rb0.y;
        Bs[bk + 2][bn0] = rb0.z;
        Bs[bk + 3][bn0] = rb0.w;
        Bs[bk + 4][bn0] = rb1.x;
        Bs[bk + 5][bn0] = rb1.y;
        Bs[bk + 6][bn0] = rb1.z;
        Bs[bk + 7][bn0] = rb1.w;
        __syncthreads();
        if (kt + 1 < NK) {   // prefetch next tile; latency hidden by inner loop
            ra  = *(const float4*)(Aptr + (size_t)(kt + 1) * BK);
            rb0 = *(const float4*)(Wptr + (size_t)(kt + 1) * BK);
            rb1 = *(const float4*)(Wptr + (size_t)(kt + 1) * BK + 4);
        }
#pragma unroll
        for (int kk = 0; kk < BK; ++kk) {
            const float4 av = *(const float4*)&As[kk][tr * 4];
            const float4 b0 = *(const float4*)&Bs[kk][tc * 4];
            const float4 b1 = *(const float4*)&Bs[kk][64 + tc * 4];
            const float aa[4] = {av.x, av.y, av.z, av.w};
            const float bb[8] = {b0.x, b0.y, b0.z, b0.w, b1.x, b1.y, b1.z, b1.w};
#pragma unroll
            for (int i = 0; i < 4; i++)
#pragma unroll
                for (int j = 0; j < 8; j++)
                    acc[i][j] = __builtin_fmaf(aa[i], bb[j], acc[i][j]);
        }
    }

    // epilogue: add (bia+bib), store float4s
    float bs[8];
#pragma unroll
    for (int j = 0; j < 4; j++) {
        bs[j]     = bia[tc * 4 + j] + bib[tc * 4 + j];
        bs[j + 4] = bia[64 + tc * 4 + j] + bib[64 + tc * 4 + j];
    }
#pragma unroll
    for (int i = 0; i < 4; i++) {
        const size_t r = m0 + tr * 4 + i;
        float4 o0 = {acc[i][0] + bs[0], acc[i][1] + bs[1],
                     acc[i][2] + bs[2], acc[i][3] + bs[3]};
        float4 o1 = {acc[i][4] + bs[4], acc[i][5] + bs[5],
                     acc[i][6] + bs[6], acc[i][7] + bs[7]};
        *(float4*)&out[r * HH + tc * 4]      = o0;
        *(float4*)&out[r * HH + 64 + tc * 4] = o1;
    }
}

// ---------------------------------------------------------------------------
// Sequential scan: one block per batch element b. 512 threads = 8 waves.
// lane = jj*8+kq within wave; output j = wave*8+jj; k-range = kq*16..+15.
// W_hh rows live in VGPRs (16 floats/lane); h broadcast from LDS
// (segment stride 20 floats -> conflict-free b128 broadcast reads);
// double-buffered h -> single barrier per step.
// store_h=1: write h_t to hout (layer 1). store_h=0: fused FC -> outv (layer 2).
// ---------------------------------------------------------------------------
__global__ __launch_bounds__(512) void rnn_scan_kernel(
    const float* __restrict__ pre,   // [64][512][128]
    const float* __restrict__ Whh,   // [128][128]
    float* __restrict__ hout,        // [64][512][128] (used iff store_h)
    const float* __restrict__ Wfc,   // [128]
    const float* __restrict__ bfc,   // [1]
    float* __restrict__ outv,        // [64]
    const int store_h)
{
    __shared__ float hsh[2][160];    // 8 segments x (16 + 4 pad)
    __shared__ float wsum[8];

    const int tid  = threadIdx.x;
    const int wave = tid >> 6;
    const int lane = tid & 63;
    const int jj   = lane >> 3;      // 0..7
    const int kq   = lane & 7;       // 0..7 : k-split
    const int j    = wave * 8 + jj;  // output index 0..127 (wave*8 covers 0..63... )
    const int b    = blockIdx.x;

    // NOTE: 8 waves * 8 jj = 64 outputs -> need 128: wave covers 16 outputs? No:
    // use wave*8+jj only reaches 63. Instead map j over (wave,jj) as wave*8+jj
    // is wrong; correct: j = wave * 16 ... -- we use 8 waves * 8 jj = 64.
    // FIX: each lane handles TWO outputs j and j+64 (two W rows, two accs).
    // This keeps the 8-way k-split and conflict-free broadcast layout.

    // W rows j and j+64, k-range kq*16..+15 (4 float4s each)
    float4 Wr0[4], Wr1[4];
    {
        const float* wp0 = Whh + (size_t)j * HH + kq * 16;
        const float* wp1 = Whh + (size_t)(j + 64) * HH + kq * 16;
#pragma unroll
        for (int q = 0; q < 4; q++) {
            Wr0[q] = *(const float4*)(wp0 + q * 4);
            Wr1[q] = *(const float4*)(wp1 + q * 4);
        }
    }

    if (tid < HH) hsh[0][(tid >> 4) * 20 + (tid & 15)] = 0.0f;
    __syncthreads();

    const float* pb = pre + (size_t)b * TT * HH;
    float pre_next0 = 0.f, pre_next1 = 0.f;
    if (kq == 0) { pre_next0 = pb[j]; pre_next1 = pb[j + 64]; }
    float hlast0 = 0.f, hlast1 = 0.f;

    for (int t = 0; t < TT; ++t) {
        const float* hr = hsh[t & 1];
        float* hw = hsh[(t + 1) & 1];
        const float pre_cur0 = pre_next0, pre_cur1 = pre_next1;
        if (kq == 0 && t + 1 < TT) {
            pre_next0 = pb[(size_t)(t + 1) * HH + j];
            pre_next1 = pb[(size_t)(t + 1) * HH + j + 64];
        }
        float acc0 = 0.f, acc1 = 0.f;
#pragma unroll
        for (int q = 0; q < 4; q++) {
            const float4 hv = *(const float4*)&hr[kq * 20 + q * 4];
            acc0 = __builtin_fmaf(Wr0[q].x, hv.x, acc0);
            acc0 = __builtin_fmaf(Wr0[q].y, hv.y, acc0);
            acc0 = __builtin_fmaf(Wr0[q].z, hv.z, acc0);
            acc0 = __builtin_fmaf(Wr0[q].w, hv.w, acc0);
            acc1 = __builtin_fmaf(Wr1[q].x, hv.x, acc1);
            acc1 = __builtin_fmaf(Wr1[q].y, hv.y, acc1);
            acc1 = __builtin_fmaf(Wr1[q].z, hv.z, acc1);
            acc1 = __builtin_fmaf(Wr1[q].w, hv.w, acc1);
        }
        // reduce across kq (lane bits 0..2)
        acc0 += __shfl_xor(acc0, 1);  acc1 += __shfl_xor(acc1, 1);
        acc0 += __shfl_xor(acc0, 2);  acc1 += __shfl_xor(acc1, 2);
        acc0 += __shfl_xor(acc0, 4);  acc1 += __shfl_xor(acc1, 4);
        if (kq == 0) {
            const float h0 = tanh_fast(pre_cur0 + acc0);
            const float h1 = tanh_fast(pre_cur1 + acc1);
            hw[(j >> 4) * 20 + (j & 15)] = h0;
            hw[((j + 64) >> 4) * 20 + ((j + 64) & 15)] = h1;
            if (store_h) {
                hout[((size_t)b * TT + t) * HH + j]      = h0;
                hout[((size_t)b * TT + t) * HH + j + 64] = h1;
            }
            hlast0 = h0; hlast1 = h1;
        }
        __syncthreads();
    }

    if (!store_h) {
        float contrib = 0.f;
        if (kq == 0) contrib = hlast0 * Wfc[j] + hlast1 * Wfc[j + 64];
#pragma unroll
        for (int off = 1; off < 64; off <<= 1) contrib += __shfl_xor(contrib, off);
        if (lane == 0) wsum[wave] = contrib;
        __syncthreads();
        if (tid == 0) {
            float s = bfc[0];
#pragma unroll
            for (int w = 0; w < 8; w++) s += wsum[w];
            outv[b] = s;
        }
    }
}

// ---------------------------------------------------------------------------
extern "C" void kernel_launch(void* const* d_in, const int* in_sizes, int n_in,
                              void* d_out, int out_size, void* d_ws, size_t ws_size,
                              hipStream_t stream) {
    const float* x    = (const float*)d_in[0];
    const float* Wih1 = (const float*)d_in[1];
    const float* Whh1 = (const float*)d_in[2];
    const float* bih1 = (const float*)d_in[3];
    const float* bhh1 = (const float*)d_in[4];
    const float* Wih2 = (const float*)d_in[5];
    const float* Whh2 = (const float*)d_in[6];
    const float* bih2 = (const float*)d_in[7];
    const float* bhh2 = (const float*)d_in[8];
    const float* Wfc  = (const float*)d_in[9];
    const float* bfc  = (const float*)d_in[10];
    float* out = (float*)d_out;

    float* preA = (float*)d_ws;                    // [32768][128] fp32, reused as pre2
    float* h1b  = preA + (size_t)M1 * HH;          // [32768][128] fp32

    // layer 1: pre1 = x @ W_ih1^T + b_ih1 + b_hh1
    gemm_bias_kernel<DD><<<dim3(M1 / 64), dim3(256), 0, stream>>>(x, Wih1, bih1, bhh1, preA);
    // layer 1 scan -> h1
    rnn_scan_kernel<<<dim3(BB), dim3(512), 0, stream>>>(preA, Whh1, h1b, Wfc, bfc, out, 1);
    // layer 2: pre2 = h1 @ W_ih2^T + b_ih2 + b_hh2  (reuse preA)
    gemm_bias_kernel<HH><<<dim3(M1 / 64), dim3(256), 0, stream>>>(h1b, Wih2, bih2, bhh2, preA);
    // layer 2 scan + fused FC -> out[64]
    rnn_scan_kernel<<<dim3(BB), dim3(512), 0, stream>>>(preA, Whh2, h1b, Wfc, bfc, out, 0);
}

// Round 2
// 938.634 us; speedup vs baseline: 1.0020x; 1.0020x over previous
//
#include <hip/hip_runtime.h>
#include <cstddef>
#include <cstdint>

// Problem constants (B,T,D,H) = (64,512,2048,128)
#define BB 64
#define TT 512
#define DD 2048
#define HH 128
#define M1 (BB*TT)   // 32768 rows for both GEMMs

typedef __attribute__((ext_vector_type(8))) short bf16x8;
typedef __attribute__((ext_vector_type(4))) float f32x4;
typedef __attribute__((ext_vector_type(2))) _Float16 h2f;

__device__ __forceinline__ unsigned short f2bf(float f) {
    unsigned u = __builtin_bit_cast(unsigned, f);
    u += 0x7fffu + ((u >> 16) & 1u);          // RNE
    return (unsigned short)(u >> 16);
}
__device__ __forceinline__ float bf2f(unsigned short s) {
    return __builtin_bit_cast(float, ((unsigned)s) << 16);
}
__device__ __forceinline__ float tanh_fast(float x) {
    float e2x = __builtin_amdgcn_exp2f(x * 2.885390081777927f);
    return 1.0f - 2.0f * __builtin_amdgcn_rcpf(e2x + 1.0f);
}

// ---------------------------------------------------------------------------
// prep: split W_ih1 fp32 -> (hi, lo) bf16. hi = RNE(w); lo = RNE(w - hi).
// ---------------------------------------------------------------------------
__global__ __launch_bounds__(256) void prep_w_kernel(
    const float* __restrict__ W,
    unsigned short* __restrict__ Whi, unsigned short* __restrict__ Wlo)
{
    const int i = (blockIdx.x * 256 + threadIdx.x) * 4;
    float4 w = *(const float4*)(W + i);
    unsigned short h0 = f2bf(w.x), h1 = f2bf(w.y), h2 = f2bf(w.z), h3 = f2bf(w.w);
    unsigned short l0 = f2bf(w.x - bf2f(h0)), l1 = f2bf(w.y - bf2f(h1));
    unsigned short l2 = f2bf(w.z - bf2f(h2)), l3 = f2bf(w.w - bf2f(h3));
    ushort4 hv; hv.x = h0; hv.y = h1; hv.z = h2; hv.w = h3;
    ushort4 lv; lv.x = l0; lv.y = l1; lv.z = l2; lv.w = l3;
    *(ushort4*)(Whi + i) = hv;
    *(ushort4*)(Wlo + i) = lv;
}

// ---------------------------------------------------------------------------
// gemm1: out[m][n] = sum_k x[m][k]*W[n][k] + bia[n] + bib[n] via split-bf16
// MFMA 16x16x32. BM=64 (4 waves x 16 rows), N=128 (8 n-tiles/wave), BK=32.
// Verified layouts (m89): A[m=lane&15][k=(lane>>4)*8+j]; B[k][n=lane&15] same
// k-octet; C/D col=lane&15, row=(lane>>4)*4+r.
// ---------------------------------------------------------------------------
__global__ __launch_bounds__(256) void gemm1_mfma_kernel(
    const float* __restrict__ A, const unsigned short* __restrict__ Whi,
    const unsigned short* __restrict__ Wlo,
    const float* __restrict__ bia, const float* __restrict__ bib,
    float* __restrict__ out)
{
    constexpr int K = DD, BK = 32, NK = K / BK;   // 64 iterations
    __shared__ __align__(16) short Ah[64 * 40];   // stride 40 -> 2-way banks max
    __shared__ __align__(16) short Al[64 * 40];
    __shared__ __align__(16) short Wh[128 * 40];
    __shared__ __align__(16) short Wl[128 * 40];

    const int tid = threadIdx.x, wave = tid >> 6, lane = tid & 63;
    const size_t m0 = (size_t)blockIdx.x * 64;
    const int ar = tid >> 2, ak = (tid & 3) * 8;      // A stage: row, k0
    const int wr = tid >> 1, wk = (tid & 1) * 16;     // W stage: row, k0
    const float* Ap = A + (m0 + ar) * (size_t)K + ak;
    const unsigned short* Whp = Whi + (size_t)wr * K + wk;
    const unsigned short* Wlp = Wlo + (size_t)wr * K + wk;
    const int frow = lane & 15, fko = (lane >> 4) * 8;

    f32x4 acc[8];
#pragma unroll
    for (int i = 0; i < 8; i++) acc[i] = (f32x4){0.f, 0.f, 0.f, 0.f};

    for (int kt = 0; kt < NK; ++kt) {
        float4 a0 = *(const float4*)(Ap + kt * BK);
        float4 a1 = *(const float4*)(Ap + kt * BK + 4);
        bf16x8 wh0 = *(const bf16x8*)(Whp + kt * BK);
        bf16x8 wh1 = *(const bf16x8*)(Whp + kt * BK + 8);
        bf16x8 wl0 = *(const bf16x8*)(Wlp + kt * BK);
        bf16x8 wl1 = *(const bf16x8*)(Wlp + kt * BK + 8);
        __syncthreads();   // previous iter's fragment reads complete
        float fv[8] = {a0.x, a0.y, a0.z, a0.w, a1.x, a1.y, a1.z, a1.w};
        unsigned short h[8], l[8];
#pragma unroll
        for (int i = 0; i < 8; i++) {
            h[i] = f2bf(fv[i]);
            l[i] = f2bf(fv[i] - bf2f(h[i]));
        }
        uint2 p0, p1, q0, q1;
        p0.x = (unsigned)h[0] | ((unsigned)h[1] << 16); p0.y = (unsigned)h[2] | ((unsigned)h[3] << 16);
        p1.x = (unsigned)h[4] | ((unsigned)h[5] << 16); p1.y = (unsigned)h[6] | ((unsigned)h[7] << 16);
        q0.x = (unsigned)l[0] | ((unsigned)l[1] << 16); q0.y = (unsigned)l[2] | ((unsigned)l[3] << 16);
        q1.x = (unsigned)l[4] | ((unsigned)l[5] << 16); q1.y = (unsigned)l[6] | ((unsigned)l[7] << 16);
        *(uint2*)&Ah[ar * 40 + ak]     = p0;
        *(uint2*)&Ah[ar * 40 + ak + 4] = p1;
        *(uint2*)&Al[ar * 40 + ak]     = q0;
        *(uint2*)&Al[ar * 40 + ak + 4] = q1;
        *(bf16x8*)&Wh[wr * 40 + wk]     = wh0;
        *(bf16x8*)&Wh[wr * 40 + wk + 8] = wh1;
        *(bf16x8*)&Wl[wr * 40 + wk]     = wl0;
        *(bf16x8*)&Wl[wr * 40 + wk + 8] = wl1;
        __syncthreads();
        bf16x8 fAh = *(const bf16x8*)&Ah[(wave * 16 + frow) * 40 + fko];
        bf16x8 fAl = *(const bf16x8*)&Al[(wave * 16 + frow) * 40 + fko];
#pragma unroll
        for (int nt = 0; nt < 8; ++nt) {
            bf16x8 fWh = *(const bf16x8*)&Wh[(nt * 16 + frow) * 40 + fko];
            bf16x8 fWl = *(const bf16x8*)&Wl[(nt * 16 + frow) * 40 + fko];
            acc[nt] = __builtin_amdgcn_mfma_f32_16x16x32_bf16(fAh, fWh, acc[nt], 0, 0, 0);
            acc[nt] = __builtin_amdgcn_mfma_f32_16x16x32_bf16(fAh, fWl, acc[nt], 0, 0, 0);
            acc[nt] = __builtin_amdgcn_mfma_f32_16x16x32_bf16(fAl, fWh, acc[nt], 0, 0, 0);
        }
    }
    const int rbase = (lane >> 4) * 4;
#pragma unroll
    for (int nt = 0; nt < 8; ++nt) {
        const int col = nt * 16 + frow;
        const float bv = bia[col] + bib[col];
#pragma unroll
        for (int r = 0; r < 4; r++)
            out[(m0 + wave * 16 + rbase + r) * HH + col] = acc[nt][r] + bv;
    }
}

// ---------------------------------------------------------------------------
// gemm2 (K=128, small): fp32 VALU version from R1, unchanged.
// ---------------------------------------------------------------------------
template<int K>
__global__ __launch_bounds__(256) void gemm_bias_kernel(
    const float* __restrict__ A, const float* __restrict__ W,
    const float* __restrict__ bia, const float* __restrict__ bib,
    float* __restrict__ out)
{
    constexpr int BM = 64, BK = 16;
    constexpr int NK = K / BK;
    __shared__ float As[BK][68];
    __shared__ float Bs[BK][132];
    const int tid = threadIdx.x;
    const int tc = tid & 15, tr = tid >> 4;
    const size_t m0 = (size_t)blockIdx.x * BM;
    const int arow = tid >> 2, ak4 = (tid & 3) * 4;
    const int bn0 = tid >> 1, bk = (tid & 1) * 8;
    const float* Aptr = A + (m0 + arow) * (size_t)K + ak4;
    const float* Wptr = W + (size_t)bn0 * K + bk;
    float4 ra = *(const float4*)Aptr;
    float4 rb0 = *(const float4*)(Wptr);
    float4 rb1 = *(const float4*)(Wptr + 4);
    float acc[4][8];
#pragma unroll
    for (int i = 0; i < 4; i++)
#pragma unroll
        for (int j = 0; j < 8; j++) acc[i][j] = 0.0f;
    for (int kt = 0; kt < NK; ++kt) {
        __syncthreads();
        As[ak4 + 0][arow] = ra.x; As[ak4 + 1][arow] = ra.y;
        As[ak4 + 2][arow] = ra.z; As[ak4 + 3][arow] = ra.w;
        Bs[bk + 0][bn0] = rb0.x; Bs[bk + 1][bn0] = rb0.y;
        Bs[bk + 2][bn0] = rb0.z; Bs[bk + 3][bn0] = rb0.w;
        Bs[bk + 4][bn0] = rb1.x; Bs[bk + 5][bn0] = rb1.y;
        Bs[bk + 6][bn0] = rb1.z; Bs[bk + 7][bn0] = rb1.w;
        __syncthreads();
        if (kt + 1 < NK) {
            ra = *(const float4*)(Aptr + (size_t)(kt + 1) * BK);
            rb0 = *(const float4*)(Wptr + (size_t)(kt + 1) * BK);
            rb1 = *(const float4*)(Wptr + (size_t)(kt + 1) * BK + 4);
        }
#pragma unroll
        for (int kk = 0; kk < BK; ++kk) {
            const float4 av = *(const float4*)&As[kk][tr * 4];
            const float4 b0 = *(const float4*)&Bs[kk][tc * 4];
            const float4 b1 = *(const float4*)&Bs[kk][64 + tc * 4];
            const float aa[4] = {av.x, av.y, av.z, av.w};
            const float bb[8] = {b0.x, b0.y, b0.z, b0.w, b1.x, b1.y, b1.z, b1.w};
#pragma unroll
            for (int i = 0; i < 4; i++)
#pragma unroll
                for (int j = 0; j < 8; j++)
                    acc[i][j] = __builtin_fmaf(aa[i], bb[j], acc[i][j]);
        }
    }
    float bs[8];
#pragma unroll
    for (int j = 0; j < 4; j++) {
        bs[j] = bia[tc * 4 + j] + bib[tc * 4 + j];
        bs[j + 4] = bia[64 + tc * 4 + j] + bib[64 + tc * 4 + j];
    }
#pragma unroll
    for (int i = 0; i < 4; i++) {
        const size_t r = m0 + tr * 4 + i;
        float4 o0 = {acc[i][0] + bs[0], acc[i][1] + bs[1], acc[i][2] + bs[2], acc[i][3] + bs[3]};
        float4 o1 = {acc[i][4] + bs[4], acc[i][5] + bs[5], acc[i][6] + bs[6], acc[i][7] + bs[7]};
        *(float4*)&out[r * HH + tc * 4] = o0;
        *(float4*)&out[r * HH + 64 + tc * 4] = o1;
    }
}

// ---------------------------------------------------------------------------
// Scan: ONE wave per batch element, zero barriers (wave-synchronous).
// Lane l owns outputs j0=l, j1=l+64; W_hh rows held as packed f16 pairs in
// VGPRs (128 regs); h broadcast through 256B of LDS; v_dot2_f32_f16 does
// 2 MAC/instr -> 128 dot2/step issue-bound ~256 cyc.
// ---------------------------------------------------------------------------
__global__ __launch_bounds__(64) void rnn_scan_f16(
    const float* __restrict__ pre,   // [64][512][128]
    const float* __restrict__ Whh,   // [128][128] fp32 (converted in-kernel)
    float* __restrict__ hout,        // [64][512][128] (iff store_h)
    const float* __restrict__ Wfc, const float* __restrict__ bfc,
    float* __restrict__ outv,        // [64]
    const int store_h)
{
    __shared__ __align__(16) _Float16 hsf[HH];
    const int l = threadIdx.x;
    const int b = blockIdx.x;

    h2f W0[64], W1[64];
    {
        const float* r0 = Whh + l * HH;
        const float* r1 = Whh + (l + 64) * HH;
#pragma unroll
        for (int q = 0; q < 32; q++) {
            float4 w = *(const float4*)(r0 + q * 4);
            W0[2 * q]     = h2f{(_Float16)w.x, (_Float16)w.y};
            W0[2 * q + 1] = h2f{(_Float16)w.z, (_Float16)w.w};
            float4 v = *(const float4*)(r1 + q * 4);
            W1[2 * q]     = h2f{(_Float16)v.x, (_Float16)v.y};
            W1[2 * q + 1] = h2f{(_Float16)v.z, (_Float16)v.w};
        }
    }
    hsf[l] = (_Float16)0.f;
    hsf[l + 64] = (_Float16)0.f;

    const float* pb = pre + (size_t)b * TT * HH;
    float* hob = hout + (size_t)b * TT * HH;
    float pn0 = pb[l], pn1 = pb[l + 64];
    float fc0 = 0.f;

    for (int t = 0; t < TT; ++t) {
        const float p0 = pn0, p1 = pn1;
        if (t + 1 < TT) {
            pn0 = pb[(size_t)(t + 1) * HH + l];
            pn1 = pb[(size_t)(t + 1) * HH + l + 64];
        }
        float a0 = 0.f, a0b = 0.f, a1 = 0.f, a1b = 0.f;
#pragma unroll
        for (int q = 0; q < 16; q++) {
            uint4 hv = *(const uint4*)&hsf[q * 8];   // broadcast read
            h2f x0 = __builtin_bit_cast(h2f, hv.x);
            h2f x1 = __builtin_bit_cast(h2f, hv.y);
            h2f x2 = __builtin_bit_cast(h2f, hv.z);
            h2f x3 = __builtin_bit_cast(h2f, hv.w);
            a0  = __builtin_amdgcn_fdot2(W0[4 * q],     x0, a0,  false);
            a0b = __builtin_amdgcn_fdot2(W0[4 * q + 1], x1, a0b, false);
            a0  = __builtin_amdgcn_fdot2(W0[4 * q + 2], x2, a0,  false);
            a0b = __builtin_amdgcn_fdot2(W0[4 * q + 3], x3, a0b, false);
            a1  = __builtin_amdgcn_fdot2(W1[4 * q],     x0, a1,  false);
            a1b = __builtin_amdgcn_fdot2(W1[4 * q + 1], x1, a1b, false);
            a1  = __builtin_amdgcn_fdot2(W1[4 * q + 2], x2, a1,  false);
            a1b = __builtin_amdgcn_fdot2(W1[4 * q + 3], x3, a1b, false);
        }
        const float h0 = tanh_fast(p0 + a0 + a0b);
        const float h1 = tanh_fast(p1 + a1 + a1b);
        hsf[l] = (_Float16)h0;        // same-wave, in-order LDS: no barrier
        hsf[l + 64] = (_Float16)h1;
        if (store_h) {
            hob[(size_t)t * HH + l] = h0;
            hob[(size_t)t * HH + l + 64] = h1;
        }
        if (t == TT - 1) fc0 = h0 * Wfc[l] + h1 * Wfc[l + 64];
    }

    if (!store_h) {
#pragma unroll
        for (int off = 1; off < 64; off <<= 1) fc0 += __shfl_xor(fc0, off);
        if (l == 0) outv[b] = fc0 + bfc[0];
    }
}

// ---------------------------------------------------------------------------
extern "C" void kernel_launch(void* const* d_in, const int* in_sizes, int n_in,
                              void* d_out, int out_size, void* d_ws, size_t ws_size,
                              hipStream_t stream) {
    const float* x    = (const float*)d_in[0];
    const float* Wih1 = (const float*)d_in[1];
    const float* Whh1 = (const float*)d_in[2];
    const float* bih1 = (const float*)d_in[3];
    const float* bhh1 = (const float*)d_in[4];
    const float* Wih2 = (const float*)d_in[5];
    const float* Whh2 = (const float*)d_in[6];
    const float* bih2 = (const float*)d_in[7];
    const float* bhh2 = (const float*)d_in[8];
    const float* Wfc  = (const float*)d_in[9];
    const float* bfc  = (const float*)d_in[10];
    float* out = (float*)d_out;

    float* preA = (float*)d_ws;                    // 16 MB
    float* h1b  = preA + (size_t)M1 * HH;          // 16 MB
    // Whi/Wlo alias the head of h1b: consumed by gemm1 BEFORE scan1 writes h1b
    unsigned short* Whi = (unsigned short*)h1b;
    unsigned short* Wlo = Whi + (size_t)HH * DD;

    prep_w_kernel<<<dim3(HH * DD / 1024), dim3(256), 0, stream>>>(Wih1, Whi, Wlo);
    gemm1_mfma_kernel<<<dim3(M1 / 64), dim3(256), 0, stream>>>(x, Whi, Wlo, bih1, bhh1, preA);
    rnn_scan_f16<<<dim3(BB), dim3(64), 0, stream>>>(preA, Whh1, h1b, Wfc, bfc, out, 1);
    gemm_bias_kernel<HH><<<dim3(M1 / 64), dim3(256), 0, stream>>>(h1b, Wih2, bih2, bhh2, preA);
    rnn_scan_f16<<<dim3(BB), dim3(64), 0, stream>>>(preA, Whh2, h1b, Wfc, bfc, out, 0);
}